// Round 10
// baseline (1289.958 us; speedup 1.0000x reference)
//
#include <hip/hip_runtime.h>
#include <cmath>

#define B_  2
#define L_  2048
#define D_  1024
#define H_  16
#define FF_ 4096
#define NL_ 2
#define NT_ (B_*L_)        /* 4096 tokens */
#define ND_ (NT_*D_)       /* 4194304 */

typedef __attribute__((ext_vector_type(8))) short bf16x8;
typedef __attribute__((ext_vector_type(4))) float f32x4;

__device__ __forceinline__ short f2bf(float x){
  unsigned u = __builtin_bit_cast(unsigned, x);
  unsigned r = (u + 0x7fffu + ((u>>16)&1u)) >> 16;
  return (short)r;
}
__device__ __forceinline__ float bf2f(short s){
  unsigned u = ((unsigned)(unsigned short)s) << 16;
  return __builtin_bit_cast(float, u);
}
#define MFMA16(a,b,c) __builtin_amdgcn_mfma_f32_16x16x32_bf16(a,b,c,0,0,0)

__device__ __forceinline__ void gload16(const short* g, short* l){
  __builtin_amdgcn_global_load_lds((const __attribute__((address_space(1))) void*)g,
                                   (__attribute__((address_space(3))) void*)l, 16, 0, 0);
}

// bijective XCD swizzle: blocks sharing an A-panel land on one XCD's L2
__device__ __forceinline__ int2 xcd_swizzle(){
  int gx = gridDim.x;
  int n  = gx * gridDim.y;
  int hw = blockIdx.x + gx*blockIdx.y;
  int logical = (hw&7)*(n>>3) + (hw>>3);
  return make_int2(logical % gx, logical / gx);
}

// ---------------- RMSNorm -> split bf16 (optionally also fp32) ----------------
template<bool WF32>
__global__ __launch_bounds__(256) void k_rmsnorm_s(const float* __restrict__ in,
                                                   const float* __restrict__ w,
                                                   short* __restrict__ oh,
                                                   short* __restrict__ ol,
                                                   float* __restrict__ of){
  int row = blockIdx.x; int tid = threadIdx.x;
  float4 xv = ((const float4*)(in + (size_t)row*D_))[tid];
  float ss = xv.x*xv.x + xv.y*xv.y + xv.z*xv.z + xv.w*xv.w;
  #pragma unroll
  for (int off=32; off; off>>=1) ss += __shfl_xor(ss, off);
  __shared__ float wsum[4];
  if ((tid&63)==0) wsum[tid>>6] = ss;
  __syncthreads();
  float tot = wsum[0]+wsum[1]+wsum[2]+wsum[3];
  float scale = 1.0f / sqrtf(tot*(1.0f/(float)D_) + 1e-5f);
  float4 w4 = ((const float4*)w)[tid];
  float v[4] = {xv.x*scale*w4.x, xv.y*scale*w4.y, xv.z*scale*w4.z, xv.w*scale*w4.w};
  short4 hh, ll;
  short h0=f2bf(v[0]); hh.x=h0; ll.x=f2bf(v[0]-bf2f(h0));
  short h1=f2bf(v[1]); hh.y=h1; ll.y=f2bf(v[1]-bf2f(h1));
  short h2=f2bf(v[2]); hh.z=h2; ll.z=f2bf(v[2]-bf2f(h2));
  short h3=f2bf(v[3]); hh.w=h3; ll.w=f2bf(v[3]-bf2f(h3));
  *(short4*)(oh + (size_t)row*D_ + tid*4) = hh;
  *(short4*)(ol + (size_t)row*D_ + tid*4) = ll;
  if (WF32){
    float4 ov; ov.x=v[0]; ov.y=v[1]; ov.z=v[2]; ov.w=v[3];
    ((float4*)(of + (size_t)row*D_))[tid] = ov;
  }
}

// ---------------- weight transpose + split body: dst[n][k] = src[(kOff+k)*srcN + nOff+n] ----
__device__ __forceinline__ void wsplit_body(float (*t)[68], const float* __restrict__ src,
                                            short* __restrict__ dh, short* __restrict__ dl,
                                            int srcN, int kOff, int nOff, int KT,
                                            int bx, int by){
  int k0 = bx*64, n0v = by*64;
  int tid = threadIdx.x;
  #pragma unroll
  for (int p=0;p<4;p++){
    int r = p*16 + (tid>>4);
    int c4 = (tid&15)*4;
    float4 v = *(const float4*)(src + (size_t)(kOff + k0 + r)*srcN + nOff + n0v + c4);
    *(float4*)&t[r][c4] = v;
  }
  __syncthreads();
  int n = tid>>2, kk = (tid&3)*16;
  bf16x8 H0, L0, H1, L1;
  #pragma unroll
  for (int q=0;q<8;q++){
    float v = t[kk+q][n]; short h=f2bf(v); H0[q]=h; L0[q]=f2bf(v-bf2f(h));
  }
  #pragma unroll
  for (int q=0;q<8;q++){
    float v = t[kk+8+q][n]; short h=f2bf(v); H1[q]=h; L1[q]=f2bf(v-bf2f(h));
  }
  size_t dof = (size_t)(n0v + n)*KT + k0 + kk;
  *(bf16x8*)(dh + dof) = H0;  *(bf16x8*)(dh + dof + 8) = H1;
  *(bf16x8*)(dl + dof) = L0;  *(bf16x8*)(dl + dof + 8) = L1;
}

// single-weight wsplit (router)
__global__ __launch_bounds__(256) void k_wsplit(const float* __restrict__ src,
                                                short* __restrict__ dh,
                                                short* __restrict__ dl,
                                                int srcN, int kOff, int nOff, int KT){
  __shared__ float t[64][68];
  wsplit_body(t, src, dh, dl, srcN, kOff, nOff, KT, blockIdx.x, blockIdx.y);
}

// fused wq/wk/wv split: grid (16,16,3)
__global__ __launch_bounds__(256) void k_wsplit_qkv(const float* __restrict__ wq,
                                                    const float* __restrict__ wk,
                                                    const float* __restrict__ wv,
                                                    short* __restrict__ dh,
                                                    short* __restrict__ dl){
  __shared__ float t[64][68];
  int z = blockIdx.z;
  const float* s = (z==0)?wq:(z==1)?wk:wv;
  wsplit_body(t, s, dh + (size_t)z*1048576, dl + (size_t)z*1048576,
              1024, 0, 0, 1024, blockIdx.x, blockIdx.y);
}

// fused w1/w3/w2 split per hc: grid (32,32,3) with early-exit
__global__ __launch_bounds__(256) void k_wsplit_ffn(const float* __restrict__ w1,
                                                    const float* __restrict__ w3,
                                                    const float* __restrict__ w2,
                                                    short* __restrict__ w1h, short* __restrict__ w1l,
                                                    short* __restrict__ w3h, short* __restrict__ w3l,
                                                    short* __restrict__ w2h, short* __restrict__ w2l,
                                                    int hc){
  __shared__ float t[64][68];
  int z = blockIdx.z;
  if (z < 2){
    if (blockIdx.x >= 16) return;
    const float* s = z ? w3 : w1;
    wsplit_body(t, s, z?w3h:w1h, z?w3l:w1l, 4096, 0, hc*2048, 1024, blockIdx.x, blockIdx.y);
  } else {
    if (blockIdx.y >= 16) return;
    wsplit_body(t, w2, w2h, w2l, 1024, hc*2048, 0, 2048, blockIdx.x, blockIdx.y);
  }
}

// ---------------- QKV GEMM: 128x128 tile, BK=64 single-buffer, XCD swizzle ----------
// V columns (sel==2) written directly in vf fragment layout (kills prep_v)
__global__ __launch_bounds__(256,3) void k_qkv_mm(const short* __restrict__ Ah,
                                                  const short* __restrict__ Al,
                                                  const short* __restrict__ Wh,
                                                  const short* __restrict__ Wl,
                                                  short* __restrict__ OutH,
                                                  short* __restrict__ Vf){
  __shared__ short lds[32768];
  int tid = threadIdx.x, wid = tid>>6, lane = tid&63;
  int l15 = lane&15, l4 = lane>>4;
  int wr = wid>>1, wc = wid&1;
  int2 bxy = xcd_swizzle();
  int m0 = bxy.y*128, n0 = bxy.x*128;
  const int K = 1024;
  f32x4 acc[4][4];
  #pragma unroll
  for (int i=0;i<4;i++){
    #pragma unroll
    for (int j=0;j<4;j++) acc[i][j] = (f32x4){0.f,0.f,0.f,0.f};
  }
  const short* gsrc = (wid==0)?Ah:(wid==1)?Al:(wid==2)?Wh:Wl;
  int rb = (wid<2)? m0 : n0;
  int gcol = ((lane&7)^(lane>>3))*8;
  short* ldsw = lds + wid*8192;
  const short* gp0 = gsrc + (size_t)(rb + (lane>>3))*K + gcol;
  for (int k0=0; k0<K; k0+=64){
    const short* gp = gp0 + k0;
    #pragma unroll
    for (int lc=0; lc<16; ++lc)
      gload16(gp + (size_t)lc*8*K, ldsw + lc*512);
    __syncthreads();
    #pragma unroll
    for (int ks=0; ks<2; ++ks){
      bf16x8 af[4], alf[4], wf[4], wlf[4];
      int gs = ((ks*4 + l4) ^ (lane&7))*8;
      #pragma unroll
      for (int f=0; f<4; ++f){
        int ar = (wr*64 + f*16 + l15)*64 + gs;
        af[f]  = *(const bf16x8*)&lds[ar];
        alf[f] = *(const bf16x8*)&lds[8192 + ar];
        int wr2 = (wc*64 + f*16 + l15)*64 + gs;
        wf[f]  = *(const bf16x8*)&lds[16384 + wr2];
        wlf[f] = *(const bf16x8*)&lds[24576 + wr2];
      }
      __builtin_amdgcn_s_setprio(1);
      #pragma unroll
      for (int i=0;i<4;i++){
        #pragma unroll
        for (int j=0;j<4;j++){
          acc[i][j] = MFMA16(af[i],  wf[j],  acc[i][j]);
          acc[i][j] = MFMA16(alf[i], wf[j],  acc[i][j]);
          acc[i][j] = MFMA16(af[i],  wlf[j], acc[i][j]);
        }
      }
      __builtin_amdgcn_s_setprio(0);
    }
    __syncthreads();
  }
  int sel = n0 >> 10;
  int cb = (n0 & 1023) + wc*64;
  if (sel < 2){
    short* oh = OutH + (size_t)sel*8388608;
    short* ol = oh + 4194304;
    #pragma unroll
    for (int i=0;i<4;i++){
      #pragma unroll
      for (int j=0;j<4;j++){
        #pragma unroll
        for (int r=0;r<4;r++){
          size_t mg = (size_t)(m0 + wr*64 + i*16 + l4*4 + r);
          int ng = cb + j*16 + l15;
          float v = acc[i][j][r];
          short h = f2bf(v);
          oh[mg*1024 + ng] = h;
          ol[mg*1024 + ng] = f2bf(v - bf2f(h));
        }
      }
    }
  } else {
    #pragma unroll
    for (int i=0;i<4;i++){
      #pragma unroll
      for (int j=0;j<4;j++){
        #pragma unroll
        for (int r=0;r<4;r++){
          int mg = m0 + wr*64 + i*16 + l4*4 + r;
          int ng = cb + j*16 + l15;
          float v = acc[i][j][r];
          short hh2 = f2bf(v);
          short ll2 = f2bf(v - bf2f(hh2));
          int bb = mg >> 11, tt = mg & 2047;
          int hd = ng >> 6, kc = tt >> 5;
          int l4v = (tt>>3)&3, iv = tt&7;
          int dtv = (ng>>4)&3, l15v = ng&15;
          size_t base = ((size_t)((bb*16+hd)*64 + kc)*8 + dtv*2)*512 + (l4v*16+l15v)*8 + iv;
          Vf[base] = hh2;
          Vf[base + 512] = ll2;
        }
      }
    }
  }
}

// ---------------- 128x64-tile GEMM, BK=64 single-buffer, XCD swizzle ----------------
// EPI 1=resid(fp32 +=), 2=silu+bias fp32, 3=dual gate
template<int EPI>
__global__ __launch_bounds__(256,(EPI==3)?3:4) void k_mm64(const short* __restrict__ Ah,
                                                const short* __restrict__ Al,
                                                const short* __restrict__ Wh,
                                                const short* __restrict__ Wl,
                                                const short* __restrict__ W3h,
                                                const short* __restrict__ W3l,
                                                int K,
                                                float* __restrict__ Cf,
                                                const float* __restrict__ bias,
                                                short* __restrict__ Gh,
                                                short* __restrict__ Gl,
                                                int ldc){
  __shared__ short lds[(EPI==3)?32768:24576];
  int tid = threadIdx.x, wid = tid>>6, lane = tid&63;
  int l15 = lane&15, l4 = lane>>4;
  int2 bxy = xcd_swizzle();
  int m0 = bxy.y*128, n0 = bxy.x*64;
  f32x4 a1[2][4], a3[2][4];
  #pragma unroll
  for (int i=0;i<2;i++){
    #pragma unroll
    for (int j=0;j<4;j++){ a1[i][j]=(f32x4){0.f,0.f,0.f,0.f}; a3[i][j]=(f32x4){0.f,0.f,0.f,0.f}; }
  }
  int gcol = ((lane&7)^(lane>>3))*8;
  int l8 = lane>>3;
  const int NCH = (EPI==3)? 16 : 12;
  for (int k0=0; k0<K; k0+=64){
    for (int t=0; t<NCH; ++t){
      int c = wid*NCH + t;
      const short* sb; int row0; short* db;
      if (c < 32){
        sb = (c<16)? Ah : Al; row0 = m0 + (c&15)*8;
        db = lds + ((c<16)?0:8192) + (c&15)*512;
      } else {
        int wseg = (c-32)>>3;
        sb = (wseg==0)?Wh:(wseg==1)?Wl:(wseg==2)?W3h:W3l;
        row0 = n0 + (c&7)*8;
        db = lds + 16384 + wseg*4096 + (c&7)*512;
      }
      gload16(sb + (size_t)(row0 + l8)*K + k0 + gcol, db);
    }
    __syncthreads();
    #pragma unroll
    for (int ks=0; ks<2; ++ks){
      int gs = ((ks*4 + l4) ^ (lane&7))*8;
      bf16x8 af[2], alf[2], wh[4], wl[4];
      #pragma unroll
      for (int f=0; f<2; ++f){
        int ar = (wid*32 + f*16 + l15)*64 + gs;
        af[f]  = *(const bf16x8*)&lds[ar];
        alf[f] = *(const bf16x8*)&lds[8192 + ar];
      }
      #pragma unroll
      for (int f=0; f<4; ++f){
        int wr2 = (f*16 + l15)*64 + gs;
        wh[f] = *(const bf16x8*)&lds[16384 + wr2];
        wl[f] = *(const bf16x8*)&lds[20480 + wr2];
      }
      __builtin_amdgcn_s_setprio(1);
      #pragma unroll
      for (int i=0;i<2;i++){
        #pragma unroll
        for (int j=0;j<4;j++){
          a1[i][j] = MFMA16(af[i],  wh[j], a1[i][j]);
          a1[i][j] = MFMA16(alf[i], wh[j], a1[i][j]);
          a1[i][j] = MFMA16(af[i],  wl[j], a1[i][j]);
        }
      }
      __builtin_amdgcn_s_setprio(0);
      if (EPI==3){
        bf16x8 w3h[4], w3l[4];
        #pragma unroll
        for (int f=0; f<4; ++f){
          int wr2 = (f*16 + l15)*64 + gs;
          w3h[f] = *(const bf16x8*)&lds[24576 + wr2];
          w3l[f] = *(const bf16x8*)&lds[28672 + wr2];
        }
        __builtin_amdgcn_s_setprio(1);
        #pragma unroll
        for (int i=0;i<2;i++){
          #pragma unroll
          for (int j=0;j<4;j++){
            a3[i][j] = MFMA16(af[i],  w3h[j], a3[i][j]);
            a3[i][j] = MFMA16(alf[i], w3h[j], a3[i][j]);
            a3[i][j] = MFMA16(af[i],  w3l[j], a3[i][j]);
          }
        }
        __builtin_amdgcn_s_setprio(0);
      }
    }
    __syncthreads();
  }
  #pragma unroll
  for (int i=0;i<2;i++){
    #pragma unroll
    for (int j=0;j<4;j++){
      #pragma unroll
      for (int r=0;r<4;r++){
        size_t mg = (size_t)(m0 + wid*32 + i*16 + l4*4 + r);
        int ng = n0 + j*16 + l15;
        float v = a1[i][j][r];
        if (EPI==1){
          float* cp = Cf + mg*ldc + ng;
          *cp = *cp + v;
        } else if (EPI==2){
          float x = v + bias[ng];
          Cf[mg*ldc + ng] = x/(1.f+expf(-x));
        } else {
          float g = v/(1.f+expf(-v)) * a3[i][j][r];
          short h = f2bf(g);
          Gh[mg*2048 + ng] = h;
          Gl[mg*2048 + ng] = f2bf(g - bf2f(h));
        }
      }
    }
  }
}

// ---------------- fused: K fragment prep (rope+split) + wo weight split ----------
__global__ __launch_bounds__(256) void k_prep_k_wo(const short* __restrict__ kh,
                                                   const short* __restrict__ kl,
                                                   const float* __restrict__ cosT,
                                                   const float* __restrict__ sinT,
                                                   short* __restrict__ kf,
                                                   const float* __restrict__ wo,
                                                   short* __restrict__ woh,
                                                   short* __restrict__ wol){
  __shared__ float t[64][68];
  int x = blockIdx.x;
  if (x >= 1024){
    int idx = x - 1024;
    wsplit_body(t, wo, woh, wol, 1024, 0, 0, 1024, idx & 15, idx >> 4);
    return;
  }
  int wave = threadIdx.x>>6, lane = threadIdx.x&63;
  int t16 = (x & 31)*4 + wave;
  int bh = x >> 5; int b = bh>>4, h = bh&15;
  int l15 = lane&15, l4 = lane>>4;
  int tok = t16*16 + l15;
  const short* khp = kh + (size_t)(b*L_+tok)*D_ + h*64;
  const short* klp = kl + (size_t)(b*L_+tok)*D_ + h*64;
  int d0 = l4*8;
  bf16x8 ka  = *(const bf16x8*)(khp + d0);
  bf16x8 kb2 = *(const bf16x8*)(khp + 32 + d0);
  bf16x8 kla = *(const bf16x8*)(klp + d0);
  bf16x8 klb = *(const bf16x8*)(klp + 32 + d0);
  const float* cr = cosT + (size_t)tok*64;
  const float* sr = sinT + (size_t)tok*64;
  float c0[8], s0[8], c1[8], s1[8];
  *(float4*)&c0[0] = *(const float4*)(cr + d0);      *(float4*)&c0[4] = *(const float4*)(cr + d0 + 4);
  *(float4*)&c1[0] = *(const float4*)(cr + 32 + d0); *(float4*)&c1[4] = *(const float4*)(cr + 32 + d0 + 4);
  *(float4*)&s0[0] = *(const float4*)(sr + d0);      *(float4*)&s0[4] = *(const float4*)(sr + d0 + 4);
  *(float4*)&s1[0] = *(const float4*)(sr + 32 + d0); *(float4*)&s1[4] = *(const float4*)(sr + 32 + d0 + 4);
  bf16x8 h0, lo0, h1, lo1;
  #pragma unroll
  for (int j=0;j<8;j++){
    float k0v = bf2f(ka[j]) + bf2f(kla[j]);
    float k1v = bf2f(kb2[j]) + bf2f(klb[j]);
    float r0 = k0v*c0[j] - k1v*s0[j];
    float r1 = k1v*c1[j] + k0v*s1[j];
    short a = f2bf(r0); h0[j]=a; lo0[j]=f2bf(r0 - bf2f(a));
    short bS = f2bf(r1); h1[j]=bS; lo1[j]=f2bf(r1 - bf2f(bS));
  }
  size_t base = ((size_t)(bh*128 + t16)*4)*512 + lane*8;
  *(bf16x8*)(kf + base)        = h0;
  *(bf16x8*)(kf + base + 512)  = lo0;
  *(bf16x8*)(kf + base + 1024) = h1;
  *(bf16x8*)(kf + base + 1536) = lo1;
}

// ---------------- MFMA flash attention: 1024 blocks (1 q-tile each), single-buffer,
//                  3 blocks/CU, heavy-first order, XCD-local heads ----------------
__global__ __launch_bounds__(256) void k_attn_mfma(const short* __restrict__ qhb,
                                                   const short* __restrict__ qlb,
                                                   const short* __restrict__ kf,
                                                   const short* __restrict__ vf,
                                                   const float* __restrict__ cosT,
                                                   const float* __restrict__ sinT,
                                                   short* __restrict__ oh,
                                                   short* __restrict__ ol){
  int bid = blockIdx.x;                       // 1024 blocks
  int logical = (bid&7)*128 + (bid>>3);       // XCD k owns logical [k*128,(k+1)*128) = 4 heads
  int bh = logical>>5;
  int qt = 31 - (logical&31);                 // heavy tiles dispatched first
  int b = bh>>4, h = bh&15;
  int wave = threadIdx.x>>6, lane = threadIdx.x&63;
  int l15 = lane&15, l4 = lane>>4;
  __shared__ short kvs[16384];                // K tile 16KB | V tile 16KB (single buffer)
  __shared__ short pblob[4][2048];
  short* pb = pblob[wave];

  auto stage = [&](int kt){
    const short* kg = kf + ((size_t)(bh*128 + kt*4))*2048;
    const short* vg = vf + ((size_t)(bh*64 + kt*2))*4096;
    #pragma unroll
    for (int c=0;c<8;c++){
      int ch = wave*8 + c;
      const short* src = (ch<16)? (kg + ch*512) : (vg + (ch-16)*512);
      gload16(src + lane*8, kvs + ch*512);
    }
  };

  stage(0);   // first K/V tile in flight; Q load + RoPE overlaps its latency

  // ---- load Q rows, fused RoPE, fold 1/8, split hi/lo ----
  int tok = qt*64 + wave*16 + l15;
  const short* qhp = qhb + (size_t)(b*L_+tok)*D_ + h*64;
  const short* qlp = qlb + (size_t)(b*L_+tok)*D_ + h*64;
  int d0 = l4*8;
  bf16x8 qa  = *(const bf16x8*)(qhp + d0);
  bf16x8 qb2 = *(const bf16x8*)(qhp + 32 + d0);
  bf16x8 qla = *(const bf16x8*)(qlp + d0);
  bf16x8 qlb2= *(const bf16x8*)(qlp + 32 + d0);
  const float* cr = cosT + (size_t)tok*64;
  const float* sr = sinT + (size_t)tok*64;
  float c0[8], s0[8], c1[8], s1[8];
  *(float4*)&c0[0] = *(const float4*)(cr + d0);      *(float4*)&c0[4] = *(const float4*)(cr + d0 + 4);
  *(float4*)&c1[0] = *(const float4*)(cr + 32 + d0); *(float4*)&c1[4] = *(const float4*)(cr + 32 + d0 + 4);
  *(float4*)&s0[0] = *(const float4*)(sr + d0);      *(float4*)&s0[4] = *(const float4*)(sr + d0 + 4);
  *(float4*)&s1[0] = *(const float4*)(sr + 32 + d0); *(float4*)&s1[4] = *(const float4*)(sr + 32 + d0 + 4);
  bf16x8 qh0, ql0, qh1, ql1;
  #pragma unroll
  for (int j=0;j<8;j++){
    float q0v = bf2f(qa[j]) + bf2f(qla[j]);
    float q1v = bf2f(qb2[j]) + bf2f(qlb2[j]);
    float r0 = (q0v*c0[j] - q1v*s0[j]) * 0.125f;
    float r1 = (q1v*c1[j] + q0v*s1[j]) * 0.125f;
    short a = f2bf(r0); qh0[j]=a; ql0[j]=f2bf(r0 - bf2f(a));
    short bS = f2bf(r1); qh1[j]=bS; ql1[j]=f2bf(r1 - bf2f(bS));
  }

  f32x4 O[4];
  #pragma unroll
  for (int dt=0;dt<4;dt++) O[dt] = (f32x4){0.f,0.f,0.f,0.f};
  float m_[4] = {-1e30f,-1e30f,-1e30f,-1e30f};
  float ls[4] = {0.f,0.f,0.f,0.f};

  for (int kt=0; kt<=qt; ++kt){
    if (kt > 0){
      __builtin_amdgcn_s_barrier();       // all waves done reading kvs from prev iter
      stage(kt);
    }
    asm volatile("s_waitcnt vmcnt(0)" ::: "memory");
    __builtin_amdgcn_s_barrier();
    const short* Kl = kvs;
    const short* Vl = kvs + 8192;
    bool dtile = (kt == qt);
    // ---- QK^T ----
    f32x4 sr4[4];
    #pragma unroll
    for (int g=0; g<4; g++){
      f32x4 acc = (f32x4){0.f,0.f,0.f,0.f};
      if (!(dtile && g > wave)){
        const short* kp = Kl + g*2048 + lane*8;
        bf16x8 kh0 = *(const bf16x8*)(kp);
        bf16x8 kl0 = *(const bf16x8*)(kp + 512);
        bf16x8 kh1 = *(const bf16x8*)(kp + 1024);
        bf16x8 kl1 = *(const bf16x8*)(kp + 1536);
        __builtin_amdgcn_s_setprio(1);
        acc = MFMA16(qh0, kh0, acc); acc = MFMA16(qh1, kh1, acc);
        acc = MFMA16(ql0, kh0, acc); acc = MFMA16(ql1, kh1, acc);
        acc = MFMA16(qh0, kl0, acc); acc = MFMA16(qh1, kl1, acc);
        __builtin_amdgcn_s_setprio(0);
      }
      sr4[g] = acc;
    }
    // ---- online softmax (rows in 16-lane groups) ----
    float p_[4][4];
    #pragma unroll
    for (int r=0; r<4; r++){
      int rowrel = wave*16 + l4*4 + r;
      float mx = -1e30f;
      float sv[4];
      #pragma unroll
      for (int g=0; g<4; g++){
        float v = sr4[g][r];
        if (dtile && (g*16 + l15) > rowrel) v = -1e30f;
        sv[g] = v; mx = fmaxf(mx, v);
      }
      #pragma unroll
      for (int off=1; off<16; off<<=1) mx = fmaxf(mx, __shfl_xor(mx, off));
      float nm = fmaxf(m_[r], mx);
      float al = __expf(m_[r] - nm);
      m_[r] = nm;
      float ps = 0.f;
      #pragma unroll
      for (int g=0; g<4; g++){ float pv = __expf(sv[g] - nm); p_[g][r] = pv; ps += pv; }
      #pragma unroll
      for (int off=1; off<16; off<<=1) ps += __shfl_xor(ps, off);
      ls[r] = ls[r]*al + ps;
      #pragma unroll
      for (int dt=0; dt<4; dt++) O[dt][r] *= al;
    }
    // ---- write P hi/lo into per-wave A-frag blob ----
    #pragma unroll
    for (int g=0; g<4; g++){
      int key = g*16 + l15;
      int cc = key>>5, sub = (key>>3)&3, ii = key&7;
      #pragma unroll
      for (int r=0; r<4; r++){
        float pv = p_[g][r];
        short ph = f2bf(pv);
        short pl = f2bf(pv - bf2f(ph));
        int idx = cc*1024 + (sub*16 + l4*4 + r)*8 + ii;
        pb[idx] = ph;
        pb[idx + 512] = pl;
      }
    }
    asm volatile("s_waitcnt lgkmcnt(0)" ::: "memory");
    // ---- PV ----
    #pragma unroll
    for (int cc=0; cc<2; cc++){
      bf16x8 pah = *(const bf16x8*)(pb + cc*1024 + lane*8);
      bf16x8 pal = *(const bf16x8*)(pb + cc*1024 + 512 + lane*8);
      const short* vp = Vl + cc*4096 + lane*8;
      __builtin_amdgcn_s_setprio(1);
      #pragma unroll
      for (int dt=0; dt<4; dt++){
        bf16x8 vh = *(const bf16x8*)(vp + dt*1024);
        bf16x8 vl = *(const bf16x8*)(vp + dt*1024 + 512);
        O[dt] = MFMA16(pah, vh, O[dt]);
        O[dt] = MFMA16(pal, vh, O[dt]);
        O[dt] = MFMA16(pah, vl, O[dt]);
      }
      __builtin_amdgcn_s_setprio(0);
    }
  }
  // ---- epilogue: divide by l, store split bf16 ----
  #pragma unroll
  for (int r=0; r<4; r++){
    float inv = 1.0f / ls[r];
    size_t row = (size_t)(b*L_ + qt*64 + wave*16 + l4*4 + r);
    #pragma unroll
    for (int dt=0; dt<4; dt++){
      float v = O[dt][r]*inv;
      short hh = f2bf(v);
      oh[row*D_ + h*64 + dt*16 + l15] = hh;
      ol[row*D_ + h*64 + dt*16 + l15] = f2bf(v - bf2f(hh));
    }
  }
}

// ---------------- logits GEMV ----------------
__global__ __launch_bounds__(256) void k_gemv(const float* __restrict__ T,
                                              const float* __restrict__ rw2,
                                              const float* __restrict__ rb2,
                                              float* __restrict__ logits){
  int row = blockIdx.x; int tid = threadIdx.x;
  float4 tv = ((const float4*)(T + (size_t)row*D_))[tid];
  float4 wv = ((const float4*)rw2)[tid];
  float s = tv.x*wv.x + tv.y*wv.y + tv.z*wv.z + tv.w*wv.w;
  #pragma unroll
  for (int off=32; off; off>>=1) s += __shfl_xor(s, off);
  __shared__ float ps[4];
  if ((tid&63)==0) ps[tid>>6] = s;
  __syncthreads();
  if (tid==0) logits[row] = ps[0]+ps[1]+ps[2]+ps[3] + rb2[0];
}

// ---------------- boundary decisions + prefix sum + positions ----------------
__global__ __launch_bounds__(256) void k_boundary(const float* __restrict__ logits,
                                                  float* __restrict__ pos_out,
                                                  int* __restrict__ hard,
                                                  int* __restrict__ cums,
                                                  int* __restrict__ counts){
  int b = blockIdx.x; int tid = threadIdx.x;
  __shared__ int part[256];
  int loc[8]; int s=0;
  int base = b*L_;
  #pragma unroll
  for (int j=0;j<8;j++){
    int ll = tid*8 + j;
    float lg = logits[base+ll];
    int hv = (ll==0) ? 1 : ((lg > 0.0f) ? 1 : 0);
    loc[j]=hv; s+=hv;
  }
  part[tid]=s; __syncthreads();
  for (int off=1; off<256; off<<=1){
    int v = part[tid];
    int add = (tid>=off) ? part[tid-off] : 0;
    __syncthreads();
    part[tid] = v + add;
    __syncthreads();
  }
  int total = part[255];
  int run = part[tid] - s;
  #pragma unroll
  for (int j=0;j<8;j++){
    int ll = tid*8+j;
    run += loc[j];
    hard[base+ll] = loc[j];
    cums[base+ll] = run;
    int idx = loc[j] ? (run-1) : (total + ll - run);
    pos_out[base+idx] = (float)ll;
  }
  if (tid==0) counts[b] = total;
}

// ---------------- scatter boundary rows of h into compressed ----------------
__global__ __launch_bounds__(256) void k_scatter(const float* __restrict__ hf,
                                                 const int* __restrict__ hard,
                                                 const int* __restrict__ cums,
                                                 float* __restrict__ comp){
  int rowid = blockIdx.x;
  if (!hard[rowid]) return;
  int b = rowid >> 11;
  int s = cums[rowid]-1;
  const float4* src = (const float4*)(hf + (size_t)rowid*D_);
  float4* dst = (float4*)(comp + (size_t)(b*L_ + s)*D_);
  dst[threadIdx.x] = src[threadIdx.x];
}

__global__ void k_finalize(const int* __restrict__ counts, float* __restrict__ out){
  if (threadIdx.x==0 && blockIdx.x==0){
    float c0 = (float)counts[0], c1 = (float)counts[1];
    out[0]=c0; out[1]=c1;
    out[2] = (float)L_ / (0.5f*(c0+c1));
  }
}

extern "C" void kernel_launch(void* const* d_in, const int* in_sizes, int n_in,
                              void* d_out, int out_size, void* d_ws, size_t ws_size,
                              hipStream_t stream){
  const float* x      = (const float*)d_in[0];
  const float* cosT   = (const float*)d_in[1];
  const float* sinT   = (const float*)d_in[2];
  const float* wq     = (const float*)d_in[3];
  const float* wk     = (const float*)d_in[4];
  const float* wv     = (const float*)d_in[5];
  const float* wo     = (const float*)d_in[6];
  const float* w1     = (const float*)d_in[7];
  const float* w2     = (const float*)d_in[8];
  const float* w3     = (const float*)d_in[9];
  const float* attn_n = (const float*)d_in[10];
  const float* mlp_n  = (const float*)d_in[11];
  const float* final_n= (const float*)d_in[12];
  const float* rw1    = (const float*)d_in[13];
  const float* rb1    = (const float*)d_in[14];
  const float* rw2    = (const float*)d_in[15];
  const float* rb2    = (const float*)d_in[16];

  float* outF = (float*)d_out;
  float* hD   = outF;                       // running + final h
  float* compD= outF + (size_t)ND_;         // oh/ol scratch, then compressed
  float* posD = outF + (size_t)2*ND_;       // boundary positions

  char* WS = (char*)d_ws;
  auto S = [&](size_t mb){ return (short*)(WS + mb*1048576ull); };
  auto F = [&](size_t mb){ return (float*)(WS + mb*1048576ull); };
  short *ah=S(0), *al=S(8);
  short *qh=S(16), *ql=S(24), *kh=S(32), *kl=S(40);
  short *qkvwt_h=S(48), *qkvwt_l=S(54);   // weights live in old vh/vl slots
  short *vf=S(64);                        // written directly by qkv_mm epilogue
  short *kf=S(48);                        // over dead qkvwt after qkv_mm
  short *wot_h=S(0), *wot_l=S(2);         // over dead ah/al during attn phase
  short *gh=S(16), *gl=S(32);
  short *w1t_h=S(48), *w1t_l=S(52), *w3t_h=S(56), *w3t_l=S(60);
  short *w2t_h=S(64), *w2t_l=S(68);
  short *rw1t_h=S(16), *rw1t_l=S(18);
  float *ra=F(20);
  float *logits=F(76);
  int *hard=(int*)(logits+NT_), *cums=hard+NT_, *cnts=cums+NT_;
  short *oh=(short*)compD, *ol=oh+4194304;

  hipMemcpyAsync(hD, x, (size_t)ND_*sizeof(float), hipMemcpyDeviceToDevice, stream);

  for (int i=0;i<NL_;++i){
    k_rmsnorm_s<false><<<NT_,256,0,stream>>>(hD, attn_n + (size_t)i*D_, ah, al, nullptr);
    k_wsplit_qkv<<<dim3(16,16,3),256,0,stream>>>(wq + (size_t)i*D_*D_, wk + (size_t)i*D_*D_,
                                                 wv + (size_t)i*D_*D_, qkvwt_h, qkvwt_l);
    k_qkv_mm<<<dim3(24,32),256,0,stream>>>(ah, al, qkvwt_h, qkvwt_l, qh, vf);
    k_prep_k_wo<<<dim3(1280),256,0,stream>>>(kh, kl, cosT, sinT, kf,
                                             wo + (size_t)i*D_*D_, wot_h, wot_l);
    k_attn_mfma<<<dim3(1024),256,0,stream>>>(qh, ql, kf, vf, cosT, sinT, oh, ol);
    k_mm64<1><<<dim3(16,32),256,0,stream>>>(oh, ol, wot_h, wot_l, nullptr, nullptr,
                                            1024, hD, nullptr, nullptr, nullptr, 1024);
    k_rmsnorm_s<false><<<NT_,256,0,stream>>>(hD, mlp_n + (size_t)i*D_, ah, al, nullptr);
    for (int hc=0; hc<2; ++hc){
      k_wsplit_ffn<<<dim3(32,32,3),256,0,stream>>>(w1 + (size_t)i*D_*FF_, w3 + (size_t)i*D_*FF_,
                                                   w2 + (size_t)i*FF_*D_,
                                                   w1t_h, w1t_l, w3t_h, w3t_l, w2t_h, w2t_l, hc);
      k_mm64<3><<<dim3(32,32),256,0,stream>>>(ah, al, w1t_h, w1t_l, w3t_h, w3t_l,
                                              1024, nullptr, nullptr, gh, gl, 0);
      k_mm64<1><<<dim3(16,32),256,0,stream>>>(gh, gl, w2t_h, w2t_l, nullptr, nullptr,
                                              2048, hD, nullptr, nullptr, nullptr, 1024);
    }
  }
  k_rmsnorm_s<true><<<NT_,256,0,stream>>>(hD, final_n, ah, al, hD);
  k_wsplit<<<dim3(16,16),256,0,stream>>>(rw1, rw1t_h, rw1t_l, 1024, 0, 0, 1024);
  k_mm64<2><<<dim3(16,32),256,0,stream>>>(ah, al, rw1t_h, rw1t_l, nullptr, nullptr,
                                          1024, ra, rb1, nullptr, nullptr, 1024);
  k_gemv<<<NT_,256,0,stream>>>(ra, rw2, rb2, logits);
  k_boundary<<<B_,256,0,stream>>>(logits, posD, hard, cums, cnts);
  hipMemsetAsync(compD, 0, (size_t)ND_*sizeof(float), stream);
  k_scatter<<<NT_,256,0,stream>>>(hD, hard, cums, compD);
  k_finalize<<<1,64,0,stream>>>(cnts, posD + NT_);
}

// Round 11
// 1242.872 us; speedup vs baseline: 1.0379x; 1.0379x over previous
//
#include <hip/hip_runtime.h>
#include <cmath>

#define B_  2
#define L_  2048
#define D_  1024
#define H_  16
#define FF_ 4096
#define NL_ 2
#define NT_ (B_*L_)        /* 4096 tokens */
#define ND_ (NT_*D_)       /* 4194304 */

typedef __attribute__((ext_vector_type(8))) short bf16x8;
typedef __attribute__((ext_vector_type(4))) float f32x4;

__device__ __forceinline__ short f2bf(float x){
  unsigned u = __builtin_bit_cast(unsigned, x);
  unsigned r = (u + 0x7fffu + ((u>>16)&1u)) >> 16;
  return (short)r;
}
__device__ __forceinline__ float bf2f(short s){
  unsigned u = ((unsigned)(unsigned short)s) << 16;
  return __builtin_bit_cast(float, u);
}
#define MFMA16(a,b,c) __builtin_amdgcn_mfma_f32_16x16x32_bf16(a,b,c,0,0,0)

__device__ __forceinline__ void gload16(const short* g, short* l){
  __builtin_amdgcn_global_load_lds((const __attribute__((address_space(1))) void*)g,
                                   (__attribute__((address_space(3))) void*)l, 16, 0, 0);
}

// bijective XCD swizzle: blocks sharing an A-panel land on one XCD's L2
__device__ __forceinline__ int2 xcd_swizzle(){
  int gx = gridDim.x;
  int n  = gx * gridDim.y;
  int hw = blockIdx.x + gx*blockIdx.y;
  int logical = (hw&7)*(n>>3) + (hw>>3);
  return make_int2(logical % gx, logical / gx);
}

// ---------------- RMSNorm -> split bf16 (optionally also fp32) ----------------
template<bool WF32>
__global__ __launch_bounds__(256) void k_rmsnorm_s(const float* __restrict__ in,
                                                   const float* __restrict__ w,
                                                   short* __restrict__ oh,
                                                   short* __restrict__ ol,
                                                   float* __restrict__ of){
  int row = blockIdx.x; int tid = threadIdx.x;
  float4 xv = ((const float4*)(in + (size_t)row*D_))[tid];
  float ss = xv.x*xv.x + xv.y*xv.y + xv.z*xv.z + xv.w*xv.w;
  #pragma unroll
  for (int off=32; off; off>>=1) ss += __shfl_xor(ss, off);
  __shared__ float wsum[4];
  if ((tid&63)==0) wsum[tid>>6] = ss;
  __syncthreads();
  float tot = wsum[0]+wsum[1]+wsum[2]+wsum[3];
  float scale = 1.0f / sqrtf(tot*(1.0f/(float)D_) + 1e-5f);
  float4 w4 = ((const float4*)w)[tid];
  float v[4] = {xv.x*scale*w4.x, xv.y*scale*w4.y, xv.z*scale*w4.z, xv.w*scale*w4.w};
  short4 hh, ll;
  short h0=f2bf(v[0]); hh.x=h0; ll.x=f2bf(v[0]-bf2f(h0));
  short h1=f2bf(v[1]); hh.y=h1; ll.y=f2bf(v[1]-bf2f(h1));
  short h2=f2bf(v[2]); hh.z=h2; ll.z=f2bf(v[2]-bf2f(h2));
  short h3=f2bf(v[3]); hh.w=h3; ll.w=f2bf(v[3]-bf2f(h3));
  *(short4*)(oh + (size_t)row*D_ + tid*4) = hh;
  *(short4*)(ol + (size_t)row*D_ + tid*4) = ll;
  if (WF32){
    float4 ov; ov.x=v[0]; ov.y=v[1]; ov.z=v[2]; ov.w=v[3];
    ((float4*)(of + (size_t)row*D_))[tid] = ov;
  }
}

// ---------------- weight transpose + split body: dst[n][k] = src[(kOff+k)*srcN + nOff+n] ----
__device__ __forceinline__ void wsplit_body(float (*t)[68], const float* __restrict__ src,
                                            short* __restrict__ dh, short* __restrict__ dl,
                                            int srcN, int kOff, int nOff, int KT,
                                            int bx, int by){
  int k0 = bx*64, n0v = by*64;
  int tid = threadIdx.x;
  #pragma unroll
  for (int p=0;p<4;p++){
    int r = p*16 + (tid>>4);
    int c4 = (tid&15)*4;
    float4 v = *(const float4*)(src + (size_t)(kOff + k0 + r)*srcN + nOff + n0v + c4);
    *(float4*)&t[r][c4] = v;
  }
  __syncthreads();
  int n = tid>>2, kk = (tid&3)*16;
  bf16x8 H0, L0, H1, L1;
  #pragma unroll
  for (int q=0;q<8;q++){
    float v = t[kk+q][n]; short h=f2bf(v); H0[q]=h; L0[q]=f2bf(v-bf2f(h));
  }
  #pragma unroll
  for (int q=0;q<8;q++){
    float v = t[kk+8+q][n]; short h=f2bf(v); H1[q]=h; L1[q]=f2bf(v-bf2f(h));
  }
  size_t dof = (size_t)(n0v + n)*KT + k0 + kk;
  *(bf16x8*)(dh + dof) = H0;  *(bf16x8*)(dh + dof + 8) = H1;
  *(bf16x8*)(dl + dof) = L0;  *(bf16x8*)(dl + dof + 8) = L1;
}

// single-weight wsplit (router)
__global__ __launch_bounds__(256) void k_wsplit(const float* __restrict__ src,
                                                short* __restrict__ dh,
                                                short* __restrict__ dl,
                                                int srcN, int kOff, int nOff, int KT){
  __shared__ float t[64][68];
  wsplit_body(t, src, dh, dl, srcN, kOff, nOff, KT, blockIdx.x, blockIdx.y);
}

// fused wq/wk/wv split: grid (16,16,3)
__global__ __launch_bounds__(256) void k_wsplit_qkv(const float* __restrict__ wq,
                                                    const float* __restrict__ wk,
                                                    const float* __restrict__ wv,
                                                    short* __restrict__ dh,
                                                    short* __restrict__ dl){
  __shared__ float t[64][68];
  int z = blockIdx.z;
  const float* s = (z==0)?wq:(z==1)?wk:wv;
  wsplit_body(t, s, dh + (size_t)z*1048576, dl + (size_t)z*1048576,
              1024, 0, 0, 1024, blockIdx.x, blockIdx.y);
}

// fused w1/w3/w2 split per hc: grid (32,32,3) with early-exit
__global__ __launch_bounds__(256) void k_wsplit_ffn(const float* __restrict__ w1,
                                                    const float* __restrict__ w3,
                                                    const float* __restrict__ w2,
                                                    short* __restrict__ w1h, short* __restrict__ w1l,
                                                    short* __restrict__ w3h, short* __restrict__ w3l,
                                                    short* __restrict__ w2h, short* __restrict__ w2l,
                                                    int hc){
  __shared__ float t[64][68];
  int z = blockIdx.z;
  if (z < 2){
    if (blockIdx.x >= 16) return;
    const float* s = z ? w3 : w1;
    wsplit_body(t, s, z?w3h:w1h, z?w3l:w1l, 4096, 0, hc*2048, 1024, blockIdx.x, blockIdx.y);
  } else {
    if (blockIdx.y >= 16) return;
    wsplit_body(t, w2, w2h, w2l, 1024, hc*2048, 0, 2048, blockIdx.x, blockIdx.y);
  }
}

// ---------------- QKV GEMM: 128x128 tile, BK=64 single-buffer, XCD swizzle ----------
// V columns (sel==2) written directly in vf fragment layout (kills prep_v)
__global__ __launch_bounds__(256,3) void k_qkv_mm(const short* __restrict__ Ah,
                                                  const short* __restrict__ Al,
                                                  const short* __restrict__ Wh,
                                                  const short* __restrict__ Wl,
                                                  short* __restrict__ OutH,
                                                  short* __restrict__ Vf){
  __shared__ short lds[32768];
  int tid = threadIdx.x, wid = tid>>6, lane = tid&63;
  int l15 = lane&15, l4 = lane>>4;
  int wr = wid>>1, wc = wid&1;
  int2 bxy = xcd_swizzle();
  int m0 = bxy.y*128, n0 = bxy.x*128;
  const int K = 1024;
  f32x4 acc[4][4];
  #pragma unroll
  for (int i=0;i<4;i++){
    #pragma unroll
    for (int j=0;j<4;j++) acc[i][j] = (f32x4){0.f,0.f,0.f,0.f};
  }
  const short* gsrc = (wid==0)?Ah:(wid==1)?Al:(wid==2)?Wh:Wl;
  int rb = (wid<2)? m0 : n0;
  int gcol = ((lane&7)^(lane>>3))*8;
  short* ldsw = lds + wid*8192;
  const short* gp0 = gsrc + (size_t)(rb + (lane>>3))*K + gcol;
  for (int k0=0; k0<K; k0+=64){
    const short* gp = gp0 + k0;
    #pragma unroll
    for (int lc=0; lc<16; ++lc)
      gload16(gp + (size_t)lc*8*K, ldsw + lc*512);
    __syncthreads();
    #pragma unroll
    for (int ks=0; ks<2; ++ks){
      bf16x8 af[4], alf[4], wf[4], wlf[4];
      int gs = ((ks*4 + l4) ^ (lane&7))*8;
      #pragma unroll
      for (int f=0; f<4; ++f){
        int ar = (wr*64 + f*16 + l15)*64 + gs;
        af[f]  = *(const bf16x8*)&lds[ar];
        alf[f] = *(const bf16x8*)&lds[8192 + ar];
        int wr2 = (wc*64 + f*16 + l15)*64 + gs;
        wf[f]  = *(const bf16x8*)&lds[16384 + wr2];
        wlf[f] = *(const bf16x8*)&lds[24576 + wr2];
      }
      __builtin_amdgcn_s_setprio(1);
      #pragma unroll
      for (int i=0;i<4;i++){
        #pragma unroll
        for (int j=0;j<4;j++){
          acc[i][j] = MFMA16(af[i],  wf[j],  acc[i][j]);
          acc[i][j] = MFMA16(alf[i], wf[j],  acc[i][j]);
          acc[i][j] = MFMA16(af[i],  wlf[j], acc[i][j]);
        }
      }
      __builtin_amdgcn_s_setprio(0);
    }
    __syncthreads();
  }
  int sel = n0 >> 10;
  int cb = (n0 & 1023) + wc*64;
  if (sel < 2){
    short* oh = OutH + (size_t)sel*8388608;
    short* ol = oh + 4194304;
    #pragma unroll
    for (int i=0;i<4;i++){
      #pragma unroll
      for (int j=0;j<4;j++){
        #pragma unroll
        for (int r=0;r<4;r++){
          size_t mg = (size_t)(m0 + wr*64 + i*16 + l4*4 + r);
          int ng = cb + j*16 + l15;
          float v = acc[i][j][r];
          short h = f2bf(v);
          oh[mg*1024 + ng] = h;
          ol[mg*1024 + ng] = f2bf(v - bf2f(h));
        }
      }
    }
  } else {
    #pragma unroll
    for (int i=0;i<4;i++){
      #pragma unroll
      for (int j=0;j<4;j++){
        #pragma unroll
        for (int r=0;r<4;r++){
          int mg = m0 + wr*64 + i*16 + l4*4 + r;
          int ng = cb + j*16 + l15;
          float v = acc[i][j][r];
          short hh2 = f2bf(v);
          short ll2 = f2bf(v - bf2f(hh2));
          int bb = mg >> 11, tt = mg & 2047;
          int hd = ng >> 6, kc = tt >> 5;
          int l4v = (tt>>3)&3, iv = tt&7;
          int dtv = (ng>>4)&3, l15v = ng&15;
          size_t base = ((size_t)((bb*16+hd)*64 + kc)*8 + dtv*2)*512 + (l4v*16+l15v)*8 + iv;
          Vf[base] = hh2;
          Vf[base + 512] = ll2;
        }
      }
    }
  }
}

// ---------------- 128x64-tile GEMM, BK=64 single-buffer, XCD swizzle ----------------
// EPI 1=resid(fp32 +=), 2=silu+bias fp32, 3=dual gate
template<int EPI>
__global__ __launch_bounds__(256,(EPI==3)?3:4) void k_mm64(const short* __restrict__ Ah,
                                                const short* __restrict__ Al,
                                                const short* __restrict__ Wh,
                                                const short* __restrict__ Wl,
                                                const short* __restrict__ W3h,
                                                const short* __restrict__ W3l,
                                                int K,
                                                float* __restrict__ Cf,
                                                const float* __restrict__ bias,
                                                short* __restrict__ Gh,
                                                short* __restrict__ Gl,
                                                int ldc){
  __shared__ short lds[(EPI==3)?32768:24576];
  int tid = threadIdx.x, wid = tid>>6, lane = tid&63;
  int l15 = lane&15, l4 = lane>>4;
  int2 bxy = xcd_swizzle();
  int m0 = bxy.y*128, n0 = bxy.x*64;
  f32x4 a1[2][4], a3[2][4];
  #pragma unroll
  for (int i=0;i<2;i++){
    #pragma unroll
    for (int j=0;j<4;j++){ a1[i][j]=(f32x4){0.f,0.f,0.f,0.f}; a3[i][j]=(f32x4){0.f,0.f,0.f,0.f}; }
  }
  int gcol = ((lane&7)^(lane>>3))*8;
  int l8 = lane>>3;
  const int NCH = (EPI==3)? 16 : 12;
  for (int k0=0; k0<K; k0+=64){
    for (int t=0; t<NCH; ++t){
      int c = wid*NCH + t;
      const short* sb; int row0; short* db;
      if (c < 32){
        sb = (c<16)? Ah : Al; row0 = m0 + (c&15)*8;
        db = lds + ((c<16)?0:8192) + (c&15)*512;
      } else {
        int wseg = (c-32)>>3;
        sb = (wseg==0)?Wh:(wseg==1)?Wl:(wseg==2)?W3h:W3l;
        row0 = n0 + (c&7)*8;
        db = lds + 16384 + wseg*4096 + (c&7)*512;
      }
      gload16(sb + (size_t)(row0 + l8)*K + k0 + gcol, db);
    }
    __syncthreads();
    #pragma unroll
    for (int ks=0; ks<2; ++ks){
      int gs = ((ks*4 + l4) ^ (lane&7))*8;
      bf16x8 af[2], alf[2], wh[4], wl[4];
      #pragma unroll
      for (int f=0; f<2; ++f){
        int ar = (wid*32 + f*16 + l15)*64 + gs;
        af[f]  = *(const bf16x8*)&lds[ar];
        alf[f] = *(const bf16x8*)&lds[8192 + ar];
      }
      #pragma unroll
      for (int f=0; f<4; ++f){
        int wr2 = (f*16 + l15)*64 + gs;
        wh[f] = *(const bf16x8*)&lds[16384 + wr2];
        wl[f] = *(const bf16x8*)&lds[20480 + wr2];
      }
      __builtin_amdgcn_s_setprio(1);
      #pragma unroll
      for (int i=0;i<2;i++){
        #pragma unroll
        for (int j=0;j<4;j++){
          a1[i][j] = MFMA16(af[i],  wh[j], a1[i][j]);
          a1[i][j] = MFMA16(alf[i], wh[j], a1[i][j]);
          a1[i][j] = MFMA16(af[i],  wl[j], a1[i][j]);
        }
      }
      __builtin_amdgcn_s_setprio(0);
      if (EPI==3){
        bf16x8 w3h[4], w3l[4];
        #pragma unroll
        for (int f=0; f<4; ++f){
          int wr2 = (f*16 + l15)*64 + gs;
          w3h[f] = *(const bf16x8*)&lds[24576 + wr2];
          w3l[f] = *(const bf16x8*)&lds[28672 + wr2];
        }
        __builtin_amdgcn_s_setprio(1);
        #pragma unroll
        for (int i=0;i<2;i++){
          #pragma unroll
          for (int j=0;j<4;j++){
            a3[i][j] = MFMA16(af[i],  w3h[j], a3[i][j]);
            a3[i][j] = MFMA16(alf[i], w3h[j], a3[i][j]);
            a3[i][j] = MFMA16(af[i],  w3l[j], a3[i][j]);
          }
        }
        __builtin_amdgcn_s_setprio(0);
      }
    }
    __syncthreads();
  }
  #pragma unroll
  for (int i=0;i<2;i++){
    #pragma unroll
    for (int j=0;j<4;j++){
      #pragma unroll
      for (int r=0;r<4;r++){
        size_t mg = (size_t)(m0 + wid*32 + i*16 + l4*4 + r);
        int ng = n0 + j*16 + l15;
        float v = a1[i][j][r];
        if (EPI==1){
          float* cp = Cf + mg*ldc + ng;
          *cp = *cp + v;
        } else if (EPI==2){
          float x = v + bias[ng];
          Cf[mg*ldc + ng] = x/(1.f+expf(-x));
        } else {
          float g = v/(1.f+expf(-v)) * a3[i][j][r];
          short h = f2bf(g);
          Gh[mg*2048 + ng] = h;
          Gl[mg*2048 + ng] = f2bf(g - bf2f(h));
        }
      }
    }
  }
}

// ---------------- fused: K fragment prep (rope+split) + wo weight split ----------
__global__ __launch_bounds__(256) void k_prep_k_wo(const short* __restrict__ kh,
                                                   const short* __restrict__ kl,
                                                   const float* __restrict__ cosT,
                                                   const float* __restrict__ sinT,
                                                   short* __restrict__ kf,
                                                   const float* __restrict__ wo,
                                                   short* __restrict__ woh,
                                                   short* __restrict__ wol){
  __shared__ float t[64][68];
  int x = blockIdx.x;
  if (x >= 1024){
    int idx = x - 1024;
    wsplit_body(t, wo, woh, wol, 1024, 0, 0, 1024, idx & 15, idx >> 4);
    return;
  }
  int wave = threadIdx.x>>6, lane = threadIdx.x&63;
  int t16 = (x & 31)*4 + wave;
  int bh = x >> 5; int b = bh>>4, h = bh&15;
  int l15 = lane&15, l4 = lane>>4;
  int tok = t16*16 + l15;
  const short* khp = kh + (size_t)(b*L_+tok)*D_ + h*64;
  const short* klp = kl + (size_t)(b*L_+tok)*D_ + h*64;
  int d0 = l4*8;
  bf16x8 ka  = *(const bf16x8*)(khp + d0);
  bf16x8 kb2 = *(const bf16x8*)(khp + 32 + d0);
  bf16x8 kla = *(const bf16x8*)(klp + d0);
  bf16x8 klb = *(const bf16x8*)(klp + 32 + d0);
  const float* cr = cosT + (size_t)tok*64;
  const float* sr = sinT + (size_t)tok*64;
  float c0[8], s0[8], c1[8], s1[8];
  *(float4*)&c0[0] = *(const float4*)(cr + d0);      *(float4*)&c0[4] = *(const float4*)(cr + d0 + 4);
  *(float4*)&c1[0] = *(const float4*)(cr + 32 + d0); *(float4*)&c1[4] = *(const float4*)(cr + 32 + d0 + 4);
  *(float4*)&s0[0] = *(const float4*)(sr + d0);      *(float4*)&s0[4] = *(const float4*)(sr + d0 + 4);
  *(float4*)&s1[0] = *(const float4*)(sr + 32 + d0); *(float4*)&s1[4] = *(const float4*)(sr + 32 + d0 + 4);
  bf16x8 h0, lo0, h1, lo1;
  #pragma unroll
  for (int j=0;j<8;j++){
    float k0v = bf2f(ka[j]) + bf2f(kla[j]);
    float k1v = bf2f(kb2[j]) + bf2f(klb[j]);
    float r0 = k0v*c0[j] - k1v*s0[j];
    float r1 = k1v*c1[j] + k0v*s1[j];
    short a = f2bf(r0); h0[j]=a; lo0[j]=f2bf(r0 - bf2f(a));
    short bS = f2bf(r1); h1[j]=bS; lo1[j]=f2bf(r1 - bf2f(bS));
  }
  size_t base = ((size_t)(bh*128 + t16)*4)*512 + lane*8;
  *(bf16x8*)(kf + base)        = h0;
  *(bf16x8*)(kf + base + 512)  = lo0;
  *(bf16x8*)(kf + base + 1024) = h1;
  *(bf16x8*)(kf + base + 1536) = lo1;
}

// ---------------- MFMA flash attention: paired q-tiles, LDS dbuf, XCD swizzle ---
__global__ __launch_bounds__(256) void k_attn_mfma(const short* __restrict__ qhb,
                                                   const short* __restrict__ qlb,
                                                   const short* __restrict__ kf,
                                                   const short* __restrict__ vf,
                                                   const float* __restrict__ cosT,
                                                   const float* __restrict__ sinT,
                                                   short* __restrict__ oh,
                                                   short* __restrict__ ol){
  int bid = blockIdx.x;                       // 512 blocks
  int logical = (bid&7)*64 + (bid>>3);        // XCD k owns 4 heads
  int bh = logical>>4, pair = logical&15;
  int b = bh>>4, h = bh&15;
  int wave = threadIdx.x>>6, lane = threadIdx.x&63;
  int l15 = lane&15, l4 = lane>>4;
  __shared__ short kvs[2][16384];             // per buf: K tile 16KB | V tile 16KB
  __shared__ short pblob[4][2048];
  short* pb = pblob[wave];

  auto stage = [&](int bufi, int kt){
    const short* kg = kf + ((size_t)(bh*128 + kt*4))*2048;
    const short* vg = vf + ((size_t)(bh*64 + kt*2))*4096;
    short* dst = kvs[bufi];
    #pragma unroll
    for (int c=0;c<8;c++){
      int ch = wave*8 + c;
      const short* src = (ch<16)? (kg + ch*512) : (vg + (ch-16)*512);
      gload16(src + lane*8, dst + ch*512);
    }
  };

  for (int half=0; half<2; ++half){
    int qt = (half==0) ? (31-pair) : pair;    // heavy tile first
    stage(0, 0);
    // ---- load Q rows, fused RoPE, fold 1/8, split hi/lo ----
    int tok = qt*64 + wave*16 + l15;
    const short* qhp = qhb + (size_t)(b*L_+tok)*D_ + h*64;
    const short* qlp = qlb + (size_t)(b*L_+tok)*D_ + h*64;
    int d0 = l4*8;
    bf16x8 qa  = *(const bf16x8*)(qhp + d0);
    bf16x8 qb2 = *(const bf16x8*)(qhp + 32 + d0);
    bf16x8 qla = *(const bf16x8*)(qlp + d0);
    bf16x8 qlb2= *(const bf16x8*)(qlp + 32 + d0);
    const float* cr = cosT + (size_t)tok*64;
    const float* sr = sinT + (size_t)tok*64;
    float c0[8], s0[8], c1[8], s1[8];
    *(float4*)&c0[0] = *(const float4*)(cr + d0);      *(float4*)&c0[4] = *(const float4*)(cr + d0 + 4);
    *(float4*)&c1[0] = *(const float4*)(cr + 32 + d0); *(float4*)&c1[4] = *(const float4*)(cr + 32 + d0 + 4);
    *(float4*)&s0[0] = *(const float4*)(sr + d0);      *(float4*)&s0[4] = *(const float4*)(sr + d0 + 4);
    *(float4*)&s1[0] = *(const float4*)(sr + 32 + d0); *(float4*)&s1[4] = *(const float4*)(sr + 32 + d0 + 4);
    bf16x8 qh0, ql0, qh1, ql1;
    #pragma unroll
    for (int j=0;j<8;j++){
      float q0v = bf2f(qa[j]) + bf2f(qla[j]);
      float q1v = bf2f(qb2[j]) + bf2f(qlb2[j]);
      float r0 = (q0v*c0[j] - q1v*s0[j]) * 0.125f;
      float r1 = (q1v*c1[j] + q0v*s1[j]) * 0.125f;
      short a = f2bf(r0); qh0[j]=a; ql0[j]=f2bf(r0 - bf2f(a));
      short bS = f2bf(r1); qh1[j]=bS; ql1[j]=f2bf(r1 - bf2f(bS));
    }

    f32x4 O[4];
    #pragma unroll
    for (int dt=0;dt<4;dt++) O[dt] = (f32x4){0.f,0.f,0.f,0.f};
    float m_[4] = {-1e30f,-1e30f,-1e30f,-1e30f};
    float ls[4] = {0.f,0.f,0.f,0.f};

    int cur = 0;
    for (int kt=0; kt<=qt; ++kt){
      bool haveNext = (kt < qt);
      if (haveNext){
        stage(cur^1, kt+1);
        asm volatile("s_waitcnt vmcnt(8)" ::: "memory");
      } else {
        asm volatile("s_waitcnt vmcnt(0)" ::: "memory");
      }
      __builtin_amdgcn_s_barrier();
      const short* Kl = kvs[cur];
      const short* Vl = kvs[cur] + 8192;
      bool dtile = (kt == qt);
      // ---- QK^T ----
      f32x4 sr4[4];
      #pragma unroll
      for (int g=0; g<4; g++){
        f32x4 acc = (f32x4){0.f,0.f,0.f,0.f};
        if (!(dtile && g > wave)){
          const short* kp = Kl + g*2048 + lane*8;
          bf16x8 kh0 = *(const bf16x8*)(kp);
          bf16x8 kl0 = *(const bf16x8*)(kp + 512);
          bf16x8 kh1 = *(const bf16x8*)(kp + 1024);
          bf16x8 kl1 = *(const bf16x8*)(kp + 1536);
          __builtin_amdgcn_s_setprio(1);
          acc = MFMA16(qh0, kh0, acc); acc = MFMA16(qh1, kh1, acc);
          acc = MFMA16(ql0, kh0, acc); acc = MFMA16(ql1, kh1, acc);
          acc = MFMA16(qh0, kl0, acc); acc = MFMA16(qh1, kl1, acc);
          __builtin_amdgcn_s_setprio(0);
        }
        sr4[g] = acc;
      }
      // ---- online softmax (rows in 16-lane groups) ----
      float p_[4][4];
      #pragma unroll
      for (int r=0; r<4; r++){
        int rowrel = wave*16 + l4*4 + r;
        float mx = -1e30f;
        float sv[4];
        #pragma unroll
        for (int g=0; g<4; g++){
          float v = sr4[g][r];
          if (dtile && (g*16 + l15) > rowrel) v = -1e30f;
          sv[g] = v; mx = fmaxf(mx, v);
        }
        #pragma unroll
        for (int off=1; off<16; off<<=1) mx = fmaxf(mx, __shfl_xor(mx, off));
        float nm = fmaxf(m_[r], mx);
        float al = __expf(m_[r] - nm);
        m_[r] = nm;
        float ps = 0.f;
        #pragma unroll
        for (int g=0; g<4; g++){ float pv = __expf(sv[g] - nm); p_[g][r] = pv; ps += pv; }
        #pragma unroll
        for (int off=1; off<16; off<<=1) ps += __shfl_xor(ps, off);
        ls[r] = ls[r]*al + ps;
        #pragma unroll
        for (int dt=0; dt<4; dt++) O[dt][r] *= al;
      }
      // ---- write P hi/lo into per-wave A-frag blob ----
      #pragma unroll
      for (int g=0; g<4; g++){
        int key = g*16 + l15;
        int cc = key>>5, sub = (key>>3)&3, ii = key&7;
        #pragma unroll
        for (int r=0; r<4; r++){
          float pv = p_[g][r];
          short ph = f2bf(pv);
          short pl = f2bf(pv - bf2f(ph));
          int idx = cc*1024 + (sub*16 + l4*4 + r)*8 + ii;
          pb[idx] = ph;
          pb[idx + 512] = pl;
        }
      }
      asm volatile("s_waitcnt lgkmcnt(0)" ::: "memory");
      // ---- PV ----
      #pragma unroll
      for (int cc=0; cc<2; cc++){
        bf16x8 pah = *(const bf16x8*)(pb + cc*1024 + lane*8);
        bf16x8 pal = *(const bf16x8*)(pb + cc*1024 + 512 + lane*8);
        const short* vp = Vl + cc*4096 + lane*8;
        __builtin_amdgcn_s_setprio(1);
        #pragma unroll
        for (int dt=0; dt<4; dt++){
          bf16x8 vh = *(const bf16x8*)(vp + dt*1024);
          bf16x8 vl = *(const bf16x8*)(vp + dt*1024 + 512);
          O[dt] = MFMA16(pah, vh, O[dt]);
          O[dt] = MFMA16(pal, vh, O[dt]);
          O[dt] = MFMA16(pah, vl, O[dt]);
        }
        __builtin_amdgcn_s_setprio(0);
      }
      __builtin_amdgcn_s_barrier();
      cur ^= 1;
    }
    // ---- epilogue: divide by l, store split bf16 ----
    #pragma unroll
    for (int r=0; r<4; r++){
      float inv = 1.0f / ls[r];
      size_t row = (size_t)(b*L_ + qt*64 + wave*16 + l4*4 + r);
      #pragma unroll
      for (int dt=0; dt<4; dt++){
        float v = O[dt][r]*inv;
        short hh = f2bf(v);
        oh[row*D_ + h*64 + dt*16 + l15] = hh;
        ol[row*D_ + h*64 + dt*16 + l15] = f2bf(v - bf2f(hh));
      }
    }
  }
}

// ---------------- logits GEMV ----------------
__global__ __launch_bounds__(256) void k_gemv(const float* __restrict__ T,
                                              const float* __restrict__ rw2,
                                              const float* __restrict__ rb2,
                                              float* __restrict__ logits){
  int row = blockIdx.x; int tid = threadIdx.x;
  float4 tv = ((const float4*)(T + (size_t)row*D_))[tid];
  float4 wv = ((const float4*)rw2)[tid];
  float s = tv.x*wv.x + tv.y*wv.y + tv.z*wv.z + tv.w*wv.w;
  #pragma unroll
  for (int off=32; off; off>>=1) s += __shfl_xor(s, off);
  __shared__ float ps[4];
  if ((tid&63)==0) ps[tid>>6] = s;
  __syncthreads();
  if (tid==0) logits[row] = ps[0]+ps[1]+ps[2]+ps[3] + rb2[0];
}

// ---------------- boundary decisions + prefix sum + positions ----------------
__global__ __launch_bounds__(256) void k_boundary(const float* __restrict__ logits,
                                                  float* __restrict__ pos_out,
                                                  int* __restrict__ hard,
                                                  int* __restrict__ cums,
                                                  int* __restrict__ counts){
  int b = blockIdx.x; int tid = threadIdx.x;
  __shared__ int part[256];
  int loc[8]; int s=0;
  int base = b*L_;
  #pragma unroll
  for (int j=0;j<8;j++){
    int ll = tid*8 + j;
    float lg = logits[base+ll];
    int hv = (ll==0) ? 1 : ((lg > 0.0f) ? 1 : 0);
    loc[j]=hv; s+=hv;
  }
  part[tid]=s; __syncthreads();
  for (int off=1; off<256; off<<=1){
    int v = part[tid];
    int add = (tid>=off) ? part[tid-off] : 0;
    __syncthreads();
    part[tid] = v + add;
    __syncthreads();
  }
  int total = part[255];
  int run = part[tid] - s;
  #pragma unroll
  for (int j=0;j<8;j++){
    int ll = tid*8+j;
    run += loc[j];
    hard[base+ll] = loc[j];
    cums[base+ll] = run;
    int idx = loc[j] ? (run-1) : (total + ll - run);
    pos_out[base+idx] = (float)ll;
  }
  if (tid==0) counts[b] = total;
}

// ---------------- scatter boundary rows of h into compressed ----------------
__global__ __launch_bounds__(256) void k_scatter(const float* __restrict__ hf,
                                                 const int* __restrict__ hard,
                                                 const int* __restrict__ cums,
                                                 float* __restrict__ comp){
  int rowid = blockIdx.x;
  if (!hard[rowid]) return;
  int b = rowid >> 11;
  int s = cums[rowid]-1;
  const float4* src = (const float4*)(hf + (size_t)rowid*D_);
  float4* dst = (float4*)(comp + (size_t)(b*L_ + s)*D_);
  dst[threadIdx.x] = src[threadIdx.x];
}

__global__ void k_finalize(const int* __restrict__ counts, float* __restrict__ out){
  if (threadIdx.x==0 && blockIdx.x==0){
    float c0 = (float)counts[0], c1 = (float)counts[1];
    out[0]=c0; out[1]=c1;
    out[2] = (float)L_ / (0.5f*(c0+c1));
  }
}

extern "C" void kernel_launch(void* const* d_in, const int* in_sizes, int n_in,
                              void* d_out, int out_size, void* d_ws, size_t ws_size,
                              hipStream_t stream){
  const float* x      = (const float*)d_in[0];
  const float* cosT   = (const float*)d_in[1];
  const float* sinT   = (const float*)d_in[2];
  const float* wq     = (const float*)d_in[3];
  const float* wk     = (const float*)d_in[4];
  const float* wv     = (const float*)d_in[5];
  const float* wo     = (const float*)d_in[6];
  const float* w1     = (const float*)d_in[7];
  const float* w2     = (const float*)d_in[8];
  const float* w3     = (const float*)d_in[9];
  const float* attn_n = (const float*)d_in[10];
  const float* mlp_n  = (const float*)d_in[11];
  const float* final_n= (const float*)d_in[12];
  const float* rw1    = (const float*)d_in[13];
  const float* rb1    = (const float*)d_in[14];
  const float* rw2    = (const float*)d_in[15];
  const float* rb2    = (const float*)d_in[16];

  float* outF = (float*)d_out;
  float* hD   = outF;                       // running + final h
  float* compD= outF + (size_t)ND_;         // oh/ol scratch, then compressed
  float* posD = outF + (size_t)2*ND_;       // boundary positions

  char* WS = (char*)d_ws;
  auto S = [&](size_t mb){ return (short*)(WS + mb*1048576ull); };
  auto F = [&](size_t mb){ return (float*)(WS + mb*1048576ull); };
  short *ah=S(0), *al=S(8);
  short *qh=S(16), *ql=S(24), *kh=S(32), *kl=S(40);
  short *qkvwt_h=S(48), *qkvwt_l=S(54);   // weights live in old vh/vl slots
  short *vf=S(64);                        // written directly by qkv_mm epilogue
  short *kf=S(48);                        // over dead qkvwt after qkv_mm
  short *wot_h=S(0), *wot_l=S(2);         // over dead ah/al during attn phase
  short *gh=S(16), *gl=S(32);
  short *w1t_h=S(48), *w1t_l=S(52), *w3t_h=S(56), *w3t_l=S(60);
  short *w2t_h=S(64), *w2t_l=S(68);
  short *rw1t_h=S(16), *rw1t_l=S(18);
  float *ra=F(20);
  float *logits=F(76);
  int *hard=(int*)(logits+NT_), *cums=hard+NT_, *cnts=cums+NT_;
  short *oh=(short*)compD, *ol=oh+4194304;

  hipMemcpyAsync(hD, x, (size_t)ND_*sizeof(float), hipMemcpyDeviceToDevice, stream);

  for (int i=0;i<NL_;++i){
    k_rmsnorm_s<false><<<NT_,256,0,stream>>>(hD, attn_n + (size_t)i*D_, ah, al, nullptr);
    k_wsplit_qkv<<<dim3(16,16,3),256,0,stream>>>(wq + (size_t)i*D_*D_, wk + (size_t)i*D_*D_,
                                                 wv + (size_t)i*D_*D_, qkvwt_h, qkvwt_l);
    k_qkv_mm<<<dim3(24,32),256,0,stream>>>(ah, al, qkvwt_h, qkvwt_l, qh, vf);
    k_prep_k_wo<<<dim3(1280),256,0,stream>>>(kh, kl, cosT, sinT, kf,
                                             wo + (size_t)i*D_*D_, wot_h, wot_l);
    k_attn_mfma<<<dim3(512),256,0,stream>>>(qh, ql, kf, vf, cosT, sinT, oh, ol);
    k_mm64<1><<<dim3(16,32),256,0,stream>>>(oh, ol, wot_h, wot_l, nullptr, nullptr,
                                            1024, hD, nullptr, nullptr, nullptr, 1024);
    k_rmsnorm_s<false><<<NT_,256,0,stream>>>(hD, mlp_n + (size_t)i*D_, ah, al, nullptr);
    for (int hc=0; hc<2; ++hc){
      k_wsplit_ffn<<<dim3(32,32,3),256,0,stream>>>(w1 + (size_t)i*D_*FF_, w3 + (size_t)i*D_*FF_,
                                                   w2 + (size_t)i*FF_*D_,
                                                   w1t_h, w1t_l, w3t_h, w3t_l, w2t_h, w2t_l, hc);
      k_mm64<3><<<dim3(32,32),256,0,stream>>>(ah, al, w1t_h, w1t_l, w3t_h, w3t_l,
                                              1024, nullptr, nullptr, gh, gl, 0);
      k_mm64<1><<<dim3(16,32),256,0,stream>>>(gh, gl, w2t_h, w2t_l, nullptr, nullptr,
                                              2048, hD, nullptr, nullptr, nullptr, 1024);
    }
  }
  k_rmsnorm_s<true><<<NT_,256,0,stream>>>(hD, final_n, ah, al, hD);
  k_wsplit<<<dim3(16,16),256,0,stream>>>(rw1, rw1t_h, rw1t_l, 1024, 0, 0, 1024);
  k_mm64<2><<<dim3(16,32),256,0,stream>>>(ah, al, rw1t_h, rw1t_l, nullptr, nullptr,
                                          1024, ra, rb1, nullptr, nullptr, 1024);
  k_gemv<<<NT_,256,0,stream>>>(ra, rw2, rb2, logits);
  k_boundary<<<B_,256,0,stream>>>(logits, posD, hard, cums, cnts);
  hipMemsetAsync(compD, 0, (size_t)ND_*sizeof(float), stream);
  k_scatter<<<NT_,256,0,stream>>>(hD, hard, cums, compD);
  k_finalize<<<1,64,0,stream>>>(cnts, posD + NT_);
}